// Round 1
// baseline (401.264 us; speedup 1.0000x reference)
//
#include <hip/hip_runtime.h>

// Problem: scaled dot-product attention, B=8, S=2048, D=512, fp32 in/out.
// Outputs concatenated in d_out: context [B,S,D] then attention_weights [B,S,S].
// Strategy: bf16 MFMA for both GEMMs (threshold is 2% rel — bf16-tolerant).
//   1. transpose_v: V fp32 [b][s][d] -> Vt bf16 [b][d][s] in d_ws (16.8 MB)
//   2. scores:      W = scale * Q K^T  (NT GEMM, 128x128x32 tiles, 16x16x32 MFMA)
//   3. softmax:     in-place row softmax on W (one block per row)
//   4. context:     C = W * V  == NT GEMM vs Vt (B-operand rows contiguous in k)

constexpr int BATCH = 8;
constexpr int SEQ = 2048;
constexpr int DIM = 512;

typedef __attribute__((ext_vector_type(8))) short bh8;    // 8 x bf16 (4 VGPRs)
typedef __attribute__((ext_vector_type(4))) float f4acc;  // MFMA 16x16 accumulator

// fp32 -> bf16 round-to-nearest-even (inputs are normal floats; no NaN handling needed)
__device__ __forceinline__ short f2bf(float f) {
  union { float f; unsigned u; } v;
  v.f = f;
  unsigned r = (v.u + 0x7FFFu + ((v.u >> 16) & 1u)) >> 16;
  return (short)r;
}

// ---------------------------------------------------------------------------
// V [B,S,D] fp32 -> Vt [B,D,S] bf16 (32x32 LDS tile transpose)
__global__ __launch_bounds__(256) void transpose_v_kernel(
    const float* __restrict__ V, unsigned short* __restrict__ Vt) {
  __shared__ float tile[32][33];  // +1 pad: conflict-free transposed read
  const int s0 = blockIdx.x * 32, d0 = blockIdx.y * 32, b = blockIdx.z;
  const float* Vb = V + (size_t)b * SEQ * DIM;
  unsigned short* Vtb = Vt + (size_t)b * DIM * SEQ;
  const int tx = threadIdx.x & 31, ty = threadIdx.x >> 5;  // 32 x 8
  for (int r = 0; r < 32; r += 8)
    tile[ty + r][tx] = Vb[(size_t)(s0 + ty + r) * DIM + (d0 + tx)];
  __syncthreads();
  for (int r = 0; r < 32; r += 8)
    Vtb[(size_t)(d0 + ty + r) * SEQ + (s0 + tx)] =
        (unsigned short)f2bf(tile[tx][ty + r]);
}

// ---------------------------------------------------------------------------
// Scores: W[b][q][k] = scale * dot(Q[b][q], K[b][k]).  NT GEMM, M=N=2048, K=512.
// Block 256 thr = 4 waves, tile 128x128, BK=32 (one mfma K-step). Each wave 64x64.
// LDS rows padded to 40 shorts (80 B = 20 banks) -> frag b128 reads <=2-way (free).
__global__ __launch_bounds__(256) void scores_kernel(
    const float* __restrict__ Q, const float* __restrict__ K,
    float* __restrict__ W) {
  __shared__ short As[128][40];
  __shared__ short Bs[128][40];
  const int bm = blockIdx.x, bn = blockIdx.y, b = blockIdx.z;
  const int tid = threadIdx.x, lane = tid & 63, wave = tid >> 6;
  const int wm = (wave & 1) * 64, wn = (wave >> 1) * 64;
  const float* Qb = Q + (size_t)b * SEQ * DIM + (size_t)(bm * 128) * DIM;
  const float* Kb = K + (size_t)b * SEQ * DIM + (size_t)(bn * 128) * DIM;
  f4acc acc[4][4] = {};
  const int fr = lane & 15, fk = (lane >> 4) * 8;  // frag row / k-offset
  for (int k0 = 0; k0 < DIM; k0 += 32) {
    // stage 128x32 fp32 of Q and K each -> bf16 LDS (convert in flight)
    for (int it = 0; it < 4; ++it) {
      int idx = it * 256 + tid;            // 1024 float4 slots
      int row = idx >> 3, c4 = (idx & 7) * 4;
      float4 q = *(const float4*)(Qb + (size_t)row * DIM + k0 + c4);
      float4 k = *(const float4*)(Kb + (size_t)row * DIM + k0 + c4);
      short* ap = &As[row][c4];
      ap[0] = f2bf(q.x); ap[1] = f2bf(q.y); ap[2] = f2bf(q.z); ap[3] = f2bf(q.w);
      short* bp = &Bs[row][c4];
      bp[0] = f2bf(k.x); bp[1] = f2bf(k.y); bp[2] = f2bf(k.z); bp[3] = f2bf(k.w);
    }
    __syncthreads();
    bh8 af[4], bfrag[4];
    for (int i = 0; i < 4; ++i) af[i]    = *(const bh8*)&As[wm + i * 16 + fr][fk];
    for (int i = 0; i < 4; ++i) bfrag[i] = *(const bh8*)&Bs[wn + i * 16 + fr][fk];
    for (int mi = 0; mi < 4; ++mi)
      for (int ni = 0; ni < 4; ++ni)
        acc[mi][ni] = __builtin_amdgcn_mfma_f32_16x16x32_bf16(
            af[mi], bfrag[ni], acc[mi][ni], 0, 0, 0);
    __syncthreads();
  }
  // epilogue: C/D layout col=lane&15, row=(lane>>4)*4+reg (verified m89/m91)
  const float scale = 0.044194173824159216f;  // 1/sqrt(512)
  float* Wb = W + (size_t)b * SEQ * SEQ + (size_t)(bm * 128) * SEQ + bn * 128;
  const int cc = lane & 15, rr = (lane >> 4) * 4;
  for (int mi = 0; mi < 4; ++mi)
    for (int ni = 0; ni < 4; ++ni)
      for (int r = 0; r < 4; ++r) {
        int row = wm + mi * 16 + rr + r;
        int col = wn + ni * 16 + cc;
        Wb[(size_t)row * SEQ + col] = acc[mi][ni][r] * scale;
      }
}

// ---------------------------------------------------------------------------
// Row softmax in place. One block (256 thr) per row of 2048 floats.
__global__ __launch_bounds__(256) void softmax_kernel(float* __restrict__ W) {
  float* Wr = W + (size_t)blockIdx.x * SEQ;
  const int tid = threadIdx.x, lane = tid & 63, wave = tid >> 6;
  float4 a = ((const float4*)Wr)[tid];
  float4 c = ((const float4*)Wr)[tid + 256];
  float m = fmaxf(fmaxf(fmaxf(a.x, a.y), fmaxf(a.z, a.w)),
                  fmaxf(fmaxf(c.x, c.y), fmaxf(c.z, c.w)));
  for (int off = 32; off > 0; off >>= 1) m = fmaxf(m, __shfl_xor(m, off));
  __shared__ float redm[4];
  if (lane == 0) redm[wave] = m;
  __syncthreads();
  m = fmaxf(fmaxf(redm[0], redm[1]), fmaxf(redm[2], redm[3]));
  a.x = __expf(a.x - m); a.y = __expf(a.y - m);
  a.z = __expf(a.z - m); a.w = __expf(a.w - m);
  c.x = __expf(c.x - m); c.y = __expf(c.y - m);
  c.z = __expf(c.z - m); c.w = __expf(c.w - m);
  float s = (a.x + a.y + a.z + a.w) + (c.x + c.y + c.z + c.w);
  for (int off = 32; off > 0; off >>= 1) s += __shfl_xor(s, off);
  __shared__ float reds[4];
  if (lane == 0) reds[wave] = s;
  __syncthreads();
  s = reds[0] + reds[1] + reds[2] + reds[3];
  const float inv = 1.0f / s;
  a.x *= inv; a.y *= inv; a.z *= inv; a.w *= inv;
  c.x *= inv; c.y *= inv; c.z *= inv; c.w *= inv;
  ((float4*)Wr)[tid] = a;
  ((float4*)Wr)[tid + 256] = c;
}

// ---------------------------------------------------------------------------
// Context: C[b][q][d] = sum_k W[b][q][k] * V[b][k][d].
// A-operand = W (fp32, convert in staging). B-operand rows from Vt[b][d][k]
// (already bf16, contiguous in k) -> same NT fragment pattern as scores.
// M=2048 (q), N=512 (d), K=2048.
__global__ __launch_bounds__(256) void context_kernel(
    const float* __restrict__ W, const unsigned short* __restrict__ Vt,
    float* __restrict__ C) {
  __shared__ short As[128][40];
  __shared__ short Bs[128][40];
  const int bm = blockIdx.x, bn = blockIdx.y, b = blockIdx.z;
  const int tid = threadIdx.x, lane = tid & 63, wave = tid >> 6;
  const int wm = (wave & 1) * 64, wn = (wave >> 1) * 64;
  const float* Ab = W + (size_t)b * SEQ * SEQ + (size_t)(bm * 128) * SEQ;
  const unsigned short* Vtb =
      Vt + (size_t)b * DIM * SEQ + (size_t)(bn * 128) * SEQ;
  f4acc acc[4][4] = {};
  const int fr = lane & 15, fk = (lane >> 4) * 8;
  for (int k0 = 0; k0 < SEQ; k0 += 32) {
    // stage A: 128x32 fp32 attention weights -> bf16
    for (int it = 0; it < 4; ++it) {
      int idx = it * 256 + tid;
      int row = idx >> 3, c4 = (idx & 7) * 4;
      float4 w4 = *(const float4*)(Ab + (size_t)row * SEQ + k0 + c4);
      short* ap = &As[row][c4];
      ap[0] = f2bf(w4.x); ap[1] = f2bf(w4.y); ap[2] = f2bf(w4.z); ap[3] = f2bf(w4.w);
    }
    // stage B: 128 d-rows x 32 k of Vt (already bf16) via 16B vector copies
    for (int it = 0; it < 2; ++it) {
      int idx = it * 256 + tid;            // 512 chunks of 8 shorts
      int row = idx >> 2, c8 = (idx & 3) * 8;
      bh8 v = *(const bh8*)(Vtb + (size_t)row * SEQ + k0 + c8);
      *(bh8*)&Bs[row][c8] = v;
    }
    __syncthreads();
    bh8 af[4], bfrag[4];
    for (int i = 0; i < 4; ++i) af[i]    = *(const bh8*)&As[wm + i * 16 + fr][fk];
    for (int i = 0; i < 4; ++i) bfrag[i] = *(const bh8*)&Bs[wn + i * 16 + fr][fk];
    for (int mi = 0; mi < 4; ++mi)
      for (int ni = 0; ni < 4; ++ni)
        acc[mi][ni] = __builtin_amdgcn_mfma_f32_16x16x32_bf16(
            af[mi], bfrag[ni], acc[mi][ni], 0, 0, 0);
    __syncthreads();
  }
  float* Cb = C + (size_t)b * SEQ * DIM + (size_t)(bm * 128) * DIM + bn * 128;
  const int cc = lane & 15, rr = (lane >> 4) * 4;
  for (int mi = 0; mi < 4; ++mi)
    for (int ni = 0; ni < 4; ++ni)
      for (int r = 0; r < 4; ++r) {
        int row = wm + mi * 16 + rr + r;
        int col = wn + ni * 16 + cc;
        Cb[(size_t)row * DIM + col] = acc[mi][ni][r];
      }
}

// ---------------------------------------------------------------------------
extern "C" void kernel_launch(void* const* d_in, const int* in_sizes, int n_in,
                              void* d_out, int out_size, void* d_ws,
                              size_t ws_size, hipStream_t stream) {
  const float* Q = (const float*)d_in[0];
  const float* K = (const float*)d_in[1];
  const float* V = (const float*)d_in[2];
  float* C = (float*)d_out;                                  // context [B,S,D]
  float* W = (float*)d_out + (size_t)BATCH * SEQ * DIM;      // weights [B,S,S]
  unsigned short* Vt = (unsigned short*)d_ws;                // bf16 [B,D,S], 16.8 MB

  transpose_v_kernel<<<dim3(SEQ / 32, DIM / 32, BATCH), 256, 0, stream>>>(V, Vt);
  scores_kernel<<<dim3(SEQ / 128, SEQ / 128, BATCH), 256, 0, stream>>>(Q, K, W);
  softmax_kernel<<<dim3(BATCH * SEQ), 256, 0, stream>>>(W);
  context_kernel<<<dim3(SEQ / 128, DIM / 128, BATCH), 256, 0, stream>>>(W, Vt, C);
}

// Round 2
// 385.649 us; speedup vs baseline: 1.0405x; 1.0405x over previous
//
#include <hip/hip_runtime.h>

// Scaled dot-product attention, B=8, S=2048, D=512, fp32 in/out.
// d_out = context [B,S,D] fp32 ++ attention_weights [B,S,S] fp32.
//
// R2 structure (m97 recipe): pre-convert operands to bf16 in d_ws, then both
// GEMMs stage via global_load_lds width-16 (no VALU in staging path).
//   1. convert_qk:  Q*scale,K fp32 -> bf16 Qbf,Kbf        (ws)
//   2. transpose_v: V fp32 [b][s][d] -> Vt bf16 [b][d][s] (ws)
//   3. scores:      W = Qbf Kbf^T   (NT, 128x128x32, 16x16x32 MFMA, glds)
//   4. softmax:     in-place fp32 row softmax; also emits bf16 Wbf (ws)
//   5. context:     C = Wbf Vt^T    (NT, same kernel shape)
// ws layout (shorts): Qbf[8.39M] Kbf[8.39M] Vt[8.39M] Wbf[33.6M] = 117.4 MB.

constexpr int BATCH = 8;
constexpr int SEQ = 2048;
constexpr int DIM = 512;
constexpr size_t QK_ELEMS = (size_t)BATCH * SEQ * DIM;  // 8,388,608

typedef __attribute__((ext_vector_type(8))) short bh8;    // 8 x bf16 (4 VGPRs)
typedef __attribute__((ext_vector_type(4))) float f4acc;  // MFMA 16x16 acc

__device__ __forceinline__ short f2bf(float f) {
  union { float f; unsigned u; } v;
  v.f = f;
  unsigned r = (v.u + 0x7FFFu + ((v.u >> 16) & 1u)) >> 16;
  return (short)r;
}

// async 16B global->LDS (DMA; LDS dest must equal wave-uniform base + lane*16)
__device__ __forceinline__ void glds16(const unsigned short* g,
                                       unsigned short* l) {
  __builtin_amdgcn_global_load_lds(
      (const __attribute__((address_space(1))) unsigned int*)g,
      (__attribute__((address_space(3))) unsigned int*)l, 16, 0, 0);
}

// ---------------------------------------------------------------------------
// Q -> Qbf*scale, K -> Kbf. 8 floats/thread, 16B bf16 stores.
__global__ __launch_bounds__(256) void convert_qk_kernel(
    const float* __restrict__ Q, const float* __restrict__ K,
    unsigned short* __restrict__ Qbf, unsigned short* __restrict__ Kbf) {
  const size_t i = ((size_t)blockIdx.x * 256 + threadIdx.x) * 8;
  const float sc = blockIdx.y ? 1.0f : 0.044194173824159216f;  // 1/sqrt(512)
  const float* src = blockIdx.y ? K : Q;
  unsigned short* dst = blockIdx.y ? Kbf : Qbf;
  float4 a = *(const float4*)(src + i);
  float4 b = *(const float4*)(src + i + 4);
  bh8 o;
  o[0] = f2bf(a.x * sc); o[1] = f2bf(a.y * sc);
  o[2] = f2bf(a.z * sc); o[3] = f2bf(a.w * sc);
  o[4] = f2bf(b.x * sc); o[5] = f2bf(b.y * sc);
  o[6] = f2bf(b.z * sc); o[7] = f2bf(b.w * sc);
  *(bh8*)(dst + i) = o;
}

// ---------------------------------------------------------------------------
// V [B,S,D] fp32 -> Vt [B,D,S] bf16 (32x32 LDS tile transpose)
__global__ __launch_bounds__(256) void transpose_v_kernel(
    const float* __restrict__ V, unsigned short* __restrict__ Vt) {
  __shared__ float tile[32][33];
  const int s0 = blockIdx.x * 32, d0 = blockIdx.y * 32, b = blockIdx.z;
  const float* Vb = V + (size_t)b * SEQ * DIM;
  unsigned short* Vtb = Vt + (size_t)b * DIM * SEQ;
  const int tx = threadIdx.x & 31, ty = threadIdx.x >> 5;  // 32 x 8
  for (int r = 0; r < 32; r += 8)
    tile[ty + r][tx] = Vb[(size_t)(s0 + ty + r) * DIM + (d0 + tx)];
  __syncthreads();
  for (int r = 0; r < 32; r += 8)
    Vtb[(size_t)(d0 + ty + r) * SEQ + (s0 + tx)] =
        (unsigned short)f2bf(tile[tx][ty + r]);
}

// ---------------------------------------------------------------------------
// Generic bf16 NT GEMM tile kernel body (A [M,Kd] bf16 rows, B [N,Kd] bf16
// rows, C fp32 [M,N]), tile 128x128xBK32, block=256 (4 waves, 64x64 each).
// LDS unpadded [128][32] shorts (64B rows): glds-compatible; fragment
// ds_read_b128 is 2-way bank-aliased = free (m136).
template <int KDIM, int NSTRIDE>
__device__ __forceinline__ void gemm_nt_body(
    const unsigned short* __restrict__ Arows,   // + bm*128 rows applied
    const unsigned short* __restrict__ Brows,   // + bn*128 rows applied
    float* __restrict__ Cout,                   // + tile origin applied
    unsigned short* As, unsigned short* Bs) {
  const int tid = threadIdx.x, lane = tid & 63, wave = tid >> 6;
  const int wm = (wave & 1) * 64, wn = (wave >> 1) * 64;
  // staging addressing: wave w covers rows [w*32, w*32+32); issue i covers
  // 16 rows; lane l -> row l/4, col (l&3)*8 shorts (lds off = lane*16B).
  const int srow = wave * 32 + (lane >> 2);
  const int scol = (lane & 3) * 8;
  const unsigned short* Ag = Arows + (size_t)srow * KDIM + scol;
  const unsigned short* Bg = Brows + (size_t)srow * KDIM + scol;
  unsigned short* Al = As + srow * 32 + scol;
  unsigned short* Bl = Bs + srow * 32 + scol;
  f4acc acc[4][4] = {};
  const int fr = lane & 15, fk = (lane >> 4) * 8;
  for (int k0 = 0; k0 < KDIM; k0 += 32) {
    glds16(Ag + k0, Al);
    glds16(Ag + k0 + (size_t)16 * KDIM, Al + 16 * 32);
    glds16(Bg + k0, Bl);
    glds16(Bg + k0 + (size_t)16 * KDIM, Bl + 16 * 32);
    __syncthreads();   // drains vmcnt (glds) before fragment reads
    bh8 af[4], bf[4];
    for (int i = 0; i < 4; ++i) af[i] = *(const bh8*)(As + (wm + i * 16 + fr) * 32 + fk);
    for (int i = 0; i < 4; ++i) bf[i] = *(const bh8*)(Bs + (wn + i * 16 + fr) * 32 + fk);
    for (int mi = 0; mi < 4; ++mi)
      for (int ni = 0; ni < 4; ++ni)
        acc[mi][ni] = __builtin_amdgcn_mfma_f32_16x16x32_bf16(
            af[mi], bf[ni], acc[mi][ni], 0, 0, 0);
    __syncthreads();
  }
  // C/D layout: col=lane&15, row=(lane>>4)*4+reg (verified m89/m91)
  const int cc = lane & 15, rr = (lane >> 4) * 4;
  for (int mi = 0; mi < 4; ++mi)
    for (int ni = 0; ni < 4; ++ni)
      for (int r = 0; r < 4; ++r)
        Cout[(size_t)(wm + mi * 16 + rr + r) * NSTRIDE + (wn + ni * 16 + cc)] =
            acc[mi][ni][r];
}

__global__ __launch_bounds__(256) void scores_kernel(
    const unsigned short* __restrict__ Qbf, const unsigned short* __restrict__ Kbf,
    float* __restrict__ W) {
  __shared__ unsigned short As[128 * 32];
  __shared__ unsigned short Bs[128 * 32];
  const int bm = blockIdx.x, bn = blockIdx.y, b = blockIdx.z;
  gemm_nt_body<DIM, SEQ>(
      Qbf + ((size_t)b * SEQ + bm * 128) * DIM,
      Kbf + ((size_t)b * SEQ + bn * 128) * DIM,
      W + (size_t)b * SEQ * SEQ + (size_t)(bm * 128) * SEQ + bn * 128, As, Bs);
}

__global__ __launch_bounds__(256) void context_kernel(
    const unsigned short* __restrict__ Wbf, const unsigned short* __restrict__ Vt,
    float* __restrict__ C) {
  __shared__ unsigned short As[128 * 32];
  __shared__ unsigned short Bs[128 * 32];
  const int bm = blockIdx.x, bn = blockIdx.y, b = blockIdx.z;
  gemm_nt_body<SEQ, DIM>(
      Wbf + ((size_t)b * SEQ + bm * 128) * SEQ,
      Vt + ((size_t)b * DIM + bn * 128) * SEQ,
      C + (size_t)b * SEQ * DIM + (size_t)(bm * 128) * DIM + bn * 128, As, Bs);
}

// ---------------------------------------------------------------------------
// Row softmax in place (fp32) + bf16 copy to Wbf. One block per row.
__global__ __launch_bounds__(256) void softmax_kernel(
    float* __restrict__ W, unsigned short* __restrict__ Wbf) {
  float* Wr = W + (size_t)blockIdx.x * SEQ;
  unsigned short* Wbr = Wbf + (size_t)blockIdx.x * SEQ;
  const int tid = threadIdx.x, lane = tid & 63, wave = tid >> 6;
  float4 a = ((const float4*)Wr)[tid];
  float4 c = ((const float4*)Wr)[tid + 256];
  float m = fmaxf(fmaxf(fmaxf(a.x, a.y), fmaxf(a.z, a.w)),
                  fmaxf(fmaxf(c.x, c.y), fmaxf(c.z, c.w)));
  for (int off = 32; off > 0; off >>= 1) m = fmaxf(m, __shfl_xor(m, off));
  __shared__ float redm[4];
  if (lane == 0) redm[wave] = m;
  __syncthreads();
  m = fmaxf(fmaxf(redm[0], redm[1]), fmaxf(redm[2], redm[3]));
  a.x = __expf(a.x - m); a.y = __expf(a.y - m);
  a.z = __expf(a.z - m); a.w = __expf(a.w - m);
  c.x = __expf(c.x - m); c.y = __expf(c.y - m);
  c.z = __expf(c.z - m); c.w = __expf(c.w - m);
  float s = (a.x + a.y + a.z + a.w) + (c.x + c.y + c.z + c.w);
  for (int off = 32; off > 0; off >>= 1) s += __shfl_xor(s, off);
  __shared__ float reds[4];
  if (lane == 0) reds[wave] = s;
  __syncthreads();
  s = reds[0] + reds[1] + reds[2] + reds[3];
  const float inv = 1.0f / s;
  a.x *= inv; a.y *= inv; a.z *= inv; a.w *= inv;
  c.x *= inv; c.y *= inv; c.z *= inv; c.w *= inv;
  ((float4*)Wr)[tid] = a;
  ((float4*)Wr)[tid + 256] = c;
  short4 ba = {f2bf(a.x), f2bf(a.y), f2bf(a.z), f2bf(a.w)};
  short4 bc = {f2bf(c.x), f2bf(c.y), f2bf(c.z), f2bf(c.w)};
  ((short4*)Wbr)[tid] = ba;
  ((short4*)Wbr)[tid + 256] = bc;
}

// ---------------------------------------------------------------------------
extern "C" void kernel_launch(void* const* d_in, const int* in_sizes, int n_in,
                              void* d_out, int out_size, void* d_ws,
                              size_t ws_size, hipStream_t stream) {
  const float* Q = (const float*)d_in[0];
  const float* K = (const float*)d_in[1];
  const float* V = (const float*)d_in[2];
  float* C = (float*)d_out;                               // context [B,S,D]
  float* W = (float*)d_out + QK_ELEMS;                    // weights [B,S,S]
  unsigned short* Qbf = (unsigned short*)d_ws;            // bf16 [B,S,D]
  unsigned short* Kbf = Qbf + QK_ELEMS;                   // bf16 [B,S,D]
  unsigned short* Vt  = Kbf + QK_ELEMS;                   // bf16 [B,D,S]
  unsigned short* Wbf = Vt + QK_ELEMS;                    // bf16 [B,S,S]

  convert_qk_kernel<<<dim3((unsigned)(QK_ELEMS / 8 / 256), 2), 256, 0, stream>>>(
      Q, K, Qbf, Kbf);
  transpose_v_kernel<<<dim3(SEQ / 32, DIM / 32, BATCH), 256, 0, stream>>>(V, Vt);
  scores_kernel<<<dim3(SEQ / 128, SEQ / 128, BATCH), 256, 0, stream>>>(Qbf, Kbf, W);
  softmax_kernel<<<dim3(BATCH * SEQ), 256, 0, stream>>>(W, Wbf);
  context_kernel<<<dim3(SEQ / 128, DIM / 128, BATCH), 256, 0, stream>>>(Wbf, Vt, C);
}

// Round 3
// 377.006 us; speedup vs baseline: 1.0643x; 1.0229x over previous
//
#include <hip/hip_runtime.h>

// Scaled dot-product attention, B=8, S=2048, D=512, fp32 in/out.
// d_out = context [B,S,D] fp32 ++ attention_weights [B,S,S] fp32.
//
// R3: BK=64 GEMM main loop (32 MFMA per barrier pair), raw scores kept bf16.
//   1. convert_qk:  Q*scale,K fp32 -> bf16 Qbf,Kbf             (ws)
//   2. transpose_v: V fp32 [b][s][d] -> Vt bf16 [b][d][s]      (ws)
//   3. scores:      Sbf = bf16(Qbf Kbf^T)  (NT, 128x128x64, glds, LDS repack)
//   4. softmax:     reads Sbf, writes W fp32 (d_out) + Wbf bf16 (ws)
//   5. context:     C = Wbf Vt^T           (NT, same main loop)

constexpr int BATCH = 8;
constexpr int SEQ = 2048;
constexpr int DIM = 512;
constexpr size_t QK_ELEMS = (size_t)BATCH * SEQ * DIM;   // 8,388,608
constexpr size_t SS_ELEMS = (size_t)BATCH * SEQ * SEQ;   // 33,554,432

typedef __attribute__((ext_vector_type(8))) short bh8;            // MFMA A/B frag
typedef __attribute__((ext_vector_type(8))) unsigned short u16x8; // 16B copy unit
typedef __attribute__((ext_vector_type(4))) float f4acc;          // MFMA C/D

__device__ __forceinline__ short f2bf(float f) {
  union { float f; unsigned u; } v;
  v.f = f;
  unsigned r = (v.u + 0x7FFFu + ((v.u >> 16) & 1u)) >> 16;
  return (short)r;
}

__device__ __forceinline__ float bf2f(unsigned short h) {
  union { unsigned u; float f; } v;
  v.u = (unsigned)h << 16;
  return v.f;
}

// async 16B global->LDS DMA; LDS dest must be wave-uniform base + lane*16
__device__ __forceinline__ void glds16(const unsigned short* g,
                                       unsigned short* l) {
  __builtin_amdgcn_global_load_lds(
      (const __attribute__((address_space(1))) unsigned int*)g,
      (__attribute__((address_space(3))) unsigned int*)l, 16, 0, 0);
}

// ---------------------------------------------------------------------------
// Q -> Qbf*scale, K -> Kbf. 8 floats/thread, 16B bf16 stores.
__global__ __launch_bounds__(256) void convert_qk_kernel(
    const float* __restrict__ Q, const float* __restrict__ K,
    unsigned short* __restrict__ Qbf, unsigned short* __restrict__ Kbf) {
  const size_t i = ((size_t)blockIdx.x * 256 + threadIdx.x) * 8;
  const float sc = blockIdx.y ? 1.0f : 0.044194173824159216f;  // 1/sqrt(512)
  const float* src = blockIdx.y ? K : Q;
  unsigned short* dst = blockIdx.y ? Kbf : Qbf;
  float4 a = *(const float4*)(src + i);
  float4 b = *(const float4*)(src + i + 4);
  bh8 o;
  o[0] = f2bf(a.x * sc); o[1] = f2bf(a.y * sc);
  o[2] = f2bf(a.z * sc); o[3] = f2bf(a.w * sc);
  o[4] = f2bf(b.x * sc); o[5] = f2bf(b.y * sc);
  o[6] = f2bf(b.z * sc); o[7] = f2bf(b.w * sc);
  *(bh8*)(dst + i) = o;
}

// ---------------------------------------------------------------------------
// V [B,S,D] fp32 -> Vt [B,D,S] bf16 (32x32 LDS tile transpose)
__global__ __launch_bounds__(256) void transpose_v_kernel(
    const float* __restrict__ V, unsigned short* __restrict__ Vt) {
  __shared__ float tile[32][33];
  const int s0 = blockIdx.x * 32, d0 = blockIdx.y * 32, b = blockIdx.z;
  const float* Vb = V + (size_t)b * SEQ * DIM;
  unsigned short* Vtb = Vt + (size_t)b * DIM * SEQ;
  const int tx = threadIdx.x & 31, ty = threadIdx.x >> 5;  // 32 x 8
  for (int r = 0; r < 32; r += 8)
    tile[ty + r][tx] = Vb[(size_t)(s0 + ty + r) * DIM + (d0 + tx)];
  __syncthreads();
  for (int r = 0; r < 32; r += 8)
    Vtb[(size_t)(d0 + ty + r) * SEQ + (s0 + tx)] =
        (unsigned short)f2bf(tile[tx][ty + r]);
}

// ---------------------------------------------------------------------------
// BK=64 NT main loop: A [M,KDIM] bf16 rows, B [N,KDIM] bf16 rows, 128x128 tile,
// 4 waves of 64x64. LDS = 4 subtiles [128][32] shorts (m97-proven layout:
// 64B rows -> fragment ds_read_b128 2-way aliased = free). 32 MFMA / barrier
// pair. sm must be 16384 shorts (32 KB).
template <int KDIM>
__device__ __forceinline__ void gemm_loop_nt(
    const unsigned short* __restrict__ A, const unsigned short* __restrict__ B,
    unsigned short* sm, f4acc acc[4][4]) {
  const int tid = threadIdx.x, lane = tid & 63, wave = tid >> 6;
  const int wm = (wave & 1) * 64, wn = (wave >> 1) * 64;
  // staging: wave w covers tile rows [w*32, w*32+32); per glds issue 16 rows;
  // lane offset in LDS = lane*16 B (glds contiguity requirement).
  const int srow = wave * 32 + (lane >> 2), scol = (lane & 3) * 8;
  const unsigned short* Ag = A + (size_t)srow * KDIM + scol;
  const unsigned short* Bg = B + (size_t)srow * KDIM + scol;
  unsigned short* As0 = sm;
  unsigned short* As1 = sm + 4096;
  unsigned short* Bs0 = sm + 8192;
  unsigned short* Bs1 = sm + 12288;
  unsigned short* Al0 = As0 + srow * 32 + scol;
  unsigned short* Al1 = As1 + srow * 32 + scol;
  unsigned short* Bl0 = Bs0 + srow * 32 + scol;
  unsigned short* Bl1 = Bs1 + srow * 32 + scol;
  const int fr = lane & 15, fk = (lane >> 4) * 8;
#pragma unroll 2
  for (int k0 = 0; k0 < KDIM; k0 += 64) {
    glds16(Ag + k0,                        Al0);
    glds16(Ag + k0 + (size_t)16 * KDIM,    Al0 + 512);
    glds16(Ag + k0 + 32,                   Al1);
    glds16(Ag + k0 + 32 + (size_t)16 * KDIM, Al1 + 512);
    glds16(Bg + k0,                        Bl0);
    glds16(Bg + k0 + (size_t)16 * KDIM,    Bl0 + 512);
    glds16(Bg + k0 + 32,                   Bl1);
    glds16(Bg + k0 + 32 + (size_t)16 * KDIM, Bl1 + 512);
    __syncthreads();  // drains vmcnt (glds) + orders LDS
    bh8 a0[4], a1[4], b0[4], b1[4];
    for (int i = 0; i < 4; ++i) {
      a0[i] = *(const bh8*)(As0 + (wm + i * 16 + fr) * 32 + fk);
      a1[i] = *(const bh8*)(As1 + (wm + i * 16 + fr) * 32 + fk);
      b0[i] = *(const bh8*)(Bs0 + (wn + i * 16 + fr) * 32 + fk);
      b1[i] = *(const bh8*)(Bs1 + (wn + i * 16 + fr) * 32 + fk);
    }
    for (int mi = 0; mi < 4; ++mi)
      for (int ni = 0; ni < 4; ++ni)
        acc[mi][ni] = __builtin_amdgcn_mfma_f32_16x16x32_bf16(
            a0[mi], b0[ni], acc[mi][ni], 0, 0, 0);
    for (int mi = 0; mi < 4; ++mi)
      for (int ni = 0; ni < 4; ++ni)
        acc[mi][ni] = __builtin_amdgcn_mfma_f32_16x16x32_bf16(
            a1[mi], b1[ni], acc[mi][ni], 0, 0, 0);
    __syncthreads();
  }
}

// ---------------------------------------------------------------------------
// Scores: Sbf[b][q][k] = bf16(dot(Qbf[q], Kbf[k])). Epilogue repacks the
// 128x128 fp32 acc into a bf16 LDS tile (reusing the 32 KB staging LDS),
// then streams it out with coalesced 16 B stores (67 MB total vs 134 fp32).
__global__ __launch_bounds__(256) void scores_kernel(
    const unsigned short* __restrict__ Qbf,
    const unsigned short* __restrict__ Kbf,
    unsigned short* __restrict__ Sbf) {
  __shared__ unsigned short sm[16384];
  const int bm = blockIdx.x, bn = blockIdx.y, b = blockIdx.z;
  const int tid = threadIdx.x, lane = tid & 63, wave = tid >> 6;
  const int wm = (wave & 1) * 64, wn = (wave >> 1) * 64;
  f4acc acc[4][4] = {};
  gemm_loop_nt<DIM>(Qbf + ((size_t)b * SEQ + bm * 128) * DIM,
                    Kbf + ((size_t)b * SEQ + bn * 128) * DIM, sm, acc);
  // acc -> bf16 LDS tile [128][128]. C/D layout: col=lane&15, row=(lane>>4)*4+r
  const int cc = lane & 15, rr = (lane >> 4) * 4;
  for (int mi = 0; mi < 4; ++mi)
    for (int ni = 0; ni < 4; ++ni)
      for (int r = 0; r < 4; ++r)
        sm[(wm + mi * 16 + rr + r) * 128 + (wn + ni * 16 + cc)] =
            (unsigned short)f2bf(acc[mi][ni][r]);
  __syncthreads();
  unsigned short* Sg =
      Sbf + (size_t)b * SEQ * SEQ + (size_t)(bm * 128) * SEQ + bn * 128;
  for (int i = 0; i < 8; ++i) {
    int idx = i * 256 + tid;
    int row = idx >> 4, g = (idx & 15) * 8;
    *(u16x8*)(Sg + (size_t)row * SEQ + g) = *(const u16x8*)(sm + row * 128 + g);
  }
}

// ---------------------------------------------------------------------------
// Context: C = Wbf * Vt^T (fp32 out, direct strided stores — only 33.5 MB).
__global__ __launch_bounds__(256) void context_kernel(
    const unsigned short* __restrict__ Wbf,
    const unsigned short* __restrict__ Vt, float* __restrict__ C) {
  __shared__ unsigned short sm[16384];
  const int bm = blockIdx.x, bn = blockIdx.y, b = blockIdx.z;
  const int tid = threadIdx.x, lane = tid & 63, wave = tid >> 6;
  const int wm = (wave & 1) * 64, wn = (wave >> 1) * 64;
  f4acc acc[4][4] = {};
  gemm_loop_nt<SEQ>(Wbf + ((size_t)b * SEQ + bm * 128) * SEQ,
                    Vt + ((size_t)b * DIM + bn * 128) * SEQ, sm, acc);
  float* Cb = C + (size_t)b * SEQ * DIM + (size_t)(bm * 128) * DIM + bn * 128;
  const int cc = lane & 15, rr = (lane >> 4) * 4;
  for (int mi = 0; mi < 4; ++mi)
    for (int ni = 0; ni < 4; ++ni)
      for (int r = 0; r < 4; ++r)
        Cb[(size_t)(wm + mi * 16 + rr + r) * DIM + (wn + ni * 16 + cc)] =
            acc[mi][ni][r];
}

// ---------------------------------------------------------------------------
// Row softmax: reads Sbf (bf16), writes W fp32 (d_out) + Wbf bf16 (ws).
// One 256-thread block per row; 8 elements/thread, all 16 B accesses.
__global__ __launch_bounds__(256) void softmax_kernel(
    const unsigned short* __restrict__ Sbf, float* __restrict__ W,
    unsigned short* __restrict__ Wbf) {
  const size_t row = blockIdx.x;
  const int tid = threadIdx.x, lane = tid & 63, wave = tid >> 6;
  u16x8 v = *(const u16x8*)(Sbf + row * SEQ + tid * 8);
  float x[8];
  for (int j = 0; j < 8; ++j) x[j] = bf2f(v[j]);
  float m = x[0];
  for (int j = 1; j < 8; ++j) m = fmaxf(m, x[j]);
  for (int off = 32; off > 0; off >>= 1) m = fmaxf(m, __shfl_xor(m, off));
  __shared__ float redm[4], reds[4];
  if (lane == 0) redm[wave] = m;
  __syncthreads();
  m = fmaxf(fmaxf(redm[0], redm[1]), fmaxf(redm[2], redm[3]));
  float s = 0.f;
  for (int j = 0; j < 8; ++j) { x[j] = __expf(x[j] - m); s += x[j]; }
  for (int off = 32; off > 0; off >>= 1) s += __shfl_xor(s, off);
  if (lane == 0) reds[wave] = s;
  __syncthreads();
  s = reds[0] + reds[1] + reds[2] + reds[3];
  const float inv = 1.0f / s;
  for (int j = 0; j < 8; ++j) x[j] *= inv;
  float4 o0 = {x[0], x[1], x[2], x[3]}, o1 = {x[4], x[5], x[6], x[7]};
  float* Wr = W + row * SEQ + tid * 8;
  *(float4*)Wr = o0;
  *(float4*)(Wr + 4) = o1;
  u16x8 ob;
  for (int j = 0; j < 8; ++j) ob[j] = (unsigned short)f2bf(x[j]);
  *(u16x8*)(Wbf + row * SEQ + tid * 8) = ob;
}

// ---------------------------------------------------------------------------
extern "C" void kernel_launch(void* const* d_in, const int* in_sizes, int n_in,
                              void* d_out, int out_size, void* d_ws,
                              size_t ws_size, hipStream_t stream) {
  const float* Q = (const float*)d_in[0];
  const float* K = (const float*)d_in[1];
  const float* V = (const float*)d_in[2];
  float* C = (float*)d_out;                      // context [B,S,D]
  float* W = (float*)d_out + QK_ELEMS;           // weights [B,S,S]
  unsigned short* Qbf = (unsigned short*)d_ws;   // bf16 [B,S,D]   16.8 MB
  unsigned short* Kbf = Qbf + QK_ELEMS;          // bf16 [B,S,D]   16.8 MB
  unsigned short* Vt  = Kbf + QK_ELEMS;          // bf16 [B,D,S]   16.8 MB
  unsigned short* Sbf = Vt + QK_ELEMS;           // bf16 [B,S,S]   67.1 MB
  unsigned short* Wbf = Sbf + SS_ELEMS;          // bf16 [B,S,S]   67.1 MB

  convert_qk_kernel<<<dim3((unsigned)(QK_ELEMS / 8 / 256), 2), 256, 0, stream>>>(
      Q, K, Qbf, Kbf);
  transpose_v_kernel<<<dim3(SEQ / 32, DIM / 32, BATCH), 256, 0, stream>>>(V, Vt);
  scores_kernel<<<dim3(SEQ / 128, SEQ / 128, BATCH), 256, 0, stream>>>(Qbf, Kbf, Sbf);
  softmax_kernel<<<dim3(BATCH * SEQ), 256, 0, stream>>>(Sbf, W, Wbf);
  context_kernel<<<dim3(SEQ / 128, DIM / 128, BATCH), 256, 0, stream>>>(Wbf, Vt, C);
}